// Round 5
// baseline (231.091 us; speedup 1.0000x reference)
//
#include <hip/hip_runtime.h>

#define TTOT 16384        // 4 * 4096 tokens
#define DDIM 2048
#define NEXP 64
#define TPB  32           // tokens per block (GEMM kernel)
#define KCH  256          // K-chunk per wave (DDIM / 8 waves)
#define NKS  8            // k-steps per wave (KCH / 32)
#define WTERM (NEXP * DDIM)   // 131072 elems per split term

typedef __attribute__((ext_vector_type(8))) short bf16x8;
typedef __attribute__((ext_vector_type(4))) float f32x4;
typedef __attribute__((ext_vector_type(4))) unsigned int u32x4;

// ---------------------------------------------------------------------------
// Exact fp32 -> 3x bf16 truncation split (proven R3/R4). x == xh + xm + xl.
// ---------------------------------------------------------------------------
__device__ __forceinline__ void split3(const f32x4 va, const f32x4 vb,
                                       bf16x8& h, bf16x8& m, bf16x8& l)
{
    const float f[8] = {va.x, va.y, va.z, va.w, vb.x, vb.y, vb.z, vb.w};
    unsigned int hu[8], mu[8], lu[8];
#pragma unroll
    for (int j = 0; j < 8; ++j) {
        const unsigned int xb = __float_as_uint(f[j]);
        const unsigned int hb = xb & 0xffff0000u;
        const float r1 = f[j] - __uint_as_float(hb);
        const unsigned int mb = __float_as_uint(r1) & 0xffff0000u;
        const float r2 = r1 - __uint_as_float(mb);
        hu[j] = hb; mu[j] = mb; lu[j] = __float_as_uint(r2);
    }
    u32x4 hw, mw, lw;
#pragma unroll
    for (int w = 0; w < 4; ++w) {
        hw[w] = (hu[2 * w] >> 16) | (hu[2 * w + 1] & 0xffff0000u);
        mw[w] = (mu[2 * w] >> 16) | (mu[2 * w + 1] & 0xffff0000u);
        lw[w] = (lu[2 * w] >> 16) | (lu[2 * w + 1] & 0xffff0000u);
    }
    h = __builtin_bit_cast(bf16x8, hw);
    m = __builtin_bit_cast(bf16x8, mw);
    l = __builtin_bit_cast(bf16x8, lw);
}

// ---------------------------------------------------------------------------
// Prep: split W [2048][64] fp32 into W4[3][256 kg][64 e][8 d] bf16 (R4 layout:
// B-fragment = one 16B load; wave's B load = 4 contiguous 256B segments).
// ---------------------------------------------------------------------------
__global__ __launch_bounds__(256)
void w_split(const float* __restrict__ W, unsigned short* __restrict__ W4)
{
    const int q = blockIdx.x * 256 + threadIdx.x;   // 0 .. 131071
    const int e = q >> 11;                          // 0..63
    const int d = q & 2047;                         // 0..2047
    const float w = W[(size_t)d * NEXP + e];
    const unsigned int xb = __float_as_uint(w);
    const unsigned int hb = xb & 0xffff0000u;
    const float r1 = w - __uint_as_float(hb);
    const unsigned int mb = __float_as_uint(r1) & 0xffff0000u;
    const float r2 = r1 - __uint_as_float(mb);
    const unsigned int lb = __float_as_uint(r2);
    const size_t o = ((size_t)(d >> 3) * 64 + e) * 8 + (d & 7);
    W4[o]             = (unsigned short)(hb >> 16);
    W4[o + WTERM]     = (unsigned short)(mb >> 16);
    W4[o + 2 * WTERM] = (unsigned short)(lb >> 16);
}

// ---------------------------------------------------------------------------
// GEMM: 512 blocks x 512 thr (8 waves). Wave wq owns K-chunk
// [wq*256, wq*256+256) for the block's 32 tokens x 64 experts. R5: A comes
// STRAIGHT from global into a depth-2 register pipeline (16 VGPR/iter x 2
// slots) -- no LDS on the A path, no barriers, no inline-asm waits. Per
// k-step source order: B(ks) loads, consume A(ks) (loaded 2 iters ago),
// issue A(ks+2), split3, 48 MFMA. In-order vmcnt gives A ~1.5-2 iterations
// (2000+ cyc) in flight vs ~900 cyc HBM latency; B's L2 latency hides under
// split3. Fully unrolled -> all pipeline slots statically indexed.
// Arithmetic bit-identical to R3/R4 (same split, same MFMA order).
// ---------------------------------------------------------------------------
__global__ __launch_bounds__(512, 4)
void moe_gemm(const float* __restrict__ x, const unsigned short* __restrict__ W4,
              float* __restrict__ out)
{
    __shared__ float L[TPB][NEXP + 1];   // 8.3 KB combine buffer (only LDS)
    const int tid  = threadIdx.x;
    const int lane = tid & 63;
    const int wq   = __builtin_amdgcn_readfirstlane(tid >> 6);  // 0..7
    const int lrow = lane & 15;          // A row (token) / B col (expert)
    const int lk   = lane >> 4;          // k-group (0..3)
    const int tokBase = blockIdx.x * TPB;
    const int kBase   = wq * KCH;

    f32x4 c[2][4];
#pragma unroll
    for (int mt = 0; mt < 2; ++mt)
#pragma unroll
        for (int nt = 0; nt < 4; ++nt)
            c[mt][nt] = (f32x4){0.0f, 0.0f, 0.0f, 0.0f};

    // A pointers: per-lane 8 floats (d = lk*8 .. +7) per M-tile
    const float* xp0 = x + (size_t)(tokBase + lrow) * DDIM + kBase + lk * 8;
    const float* xp1 = xp0 + (size_t)16 * DDIM;

    // B pointers (L2-resident W4)
    const unsigned short* bph = W4 + (size_t)(((kBase >> 3) + lk) * 512 + lrow * 8);
    const unsigned short* bpm = bph + WTERM;
    const unsigned short* bpl = bpm + WTERM;

    // depth-2 A register pipeline: slot p = ks & 1
    f32x4 a0a[2], a0b[2], a1a[2], a1b[2];
#pragma unroll
    for (int p = 0; p < 2; ++p) {
        a0a[p] = *(const f32x4*)(xp0 + p * 32);
        a0b[p] = *(const f32x4*)(xp0 + p * 32 + 4);
        a1a[p] = *(const f32x4*)(xp1 + p * 32);
        a1b[p] = *(const f32x4*)(xp1 + p * 32 + 4);
    }

#pragma unroll
    for (int ks = 0; ks < NKS; ++ks) {
        const int p = ks & 1;

        // B loads for ks, issued first (oldest vmem this iteration)
        bf16x8 bh[4], bm[4], bl[4];
#pragma unroll
        for (int nt = 0; nt < 4; ++nt) {
            bh[nt] = *(const bf16x8*)(bph + ks * 2048 + nt * 128);
            bm[nt] = *(const bf16x8*)(bpm + ks * 2048 + nt * 128);
            bl[nt] = *(const bf16x8*)(bpl + ks * 2048 + nt * 128);
        }

        // consume A(ks) from slot p, then refill slot with A(ks+2)
        const f32x4 c0a = a0a[p], c0b = a0b[p];
        const f32x4 c1a = a1a[p], c1b = a1b[p];
        if (ks + 2 < NKS) {
            a0a[p] = *(const f32x4*)(xp0 + (ks + 2) * 32);
            a0b[p] = *(const f32x4*)(xp0 + (ks + 2) * 32 + 4);
            a1a[p] = *(const f32x4*)(xp1 + (ks + 2) * 32);
            a1b[p] = *(const f32x4*)(xp1 + (ks + 2) * 32 + 4);
        }

        bf16x8 ah0, am0, al0, ah1, am1, al1;
        split3(c0a, c0b, ah0, am0, al0);
        split3(c1a, c1b, ah1, am1, al1);

        // 6 passes x 2 M x 4 N = 48 MFMA (verbatim R3 order -> bit-identical)
#pragma unroll
        for (int nt = 0; nt < 4; ++nt) c[0][nt] = __builtin_amdgcn_mfma_f32_16x16x32_bf16(ah0, bh[nt], c[0][nt], 0, 0, 0);
#pragma unroll
        for (int nt = 0; nt < 4; ++nt) c[1][nt] = __builtin_amdgcn_mfma_f32_16x16x32_bf16(ah1, bh[nt], c[1][nt], 0, 0, 0);
#pragma unroll
        for (int nt = 0; nt < 4; ++nt) c[0][nt] = __builtin_amdgcn_mfma_f32_16x16x32_bf16(ah0, bm[nt], c[0][nt], 0, 0, 0);
#pragma unroll
        for (int nt = 0; nt < 4; ++nt) c[1][nt] = __builtin_amdgcn_mfma_f32_16x16x32_bf16(ah1, bm[nt], c[1][nt], 0, 0, 0);
#pragma unroll
        for (int nt = 0; nt < 4; ++nt) c[0][nt] = __builtin_amdgcn_mfma_f32_16x16x32_bf16(am0, bh[nt], c[0][nt], 0, 0, 0);
#pragma unroll
        for (int nt = 0; nt < 4; ++nt) c[1][nt] = __builtin_amdgcn_mfma_f32_16x16x32_bf16(am1, bh[nt], c[1][nt], 0, 0, 0);
#pragma unroll
        for (int nt = 0; nt < 4; ++nt) c[0][nt] = __builtin_amdgcn_mfma_f32_16x16x32_bf16(ah0, bl[nt], c[0][nt], 0, 0, 0);
#pragma unroll
        for (int nt = 0; nt < 4; ++nt) c[1][nt] = __builtin_amdgcn_mfma_f32_16x16x32_bf16(ah1, bl[nt], c[1][nt], 0, 0, 0);
#pragma unroll
        for (int nt = 0; nt < 4; ++nt) c[0][nt] = __builtin_amdgcn_mfma_f32_16x16x32_bf16(al0, bh[nt], c[0][nt], 0, 0, 0);
#pragma unroll
        for (int nt = 0; nt < 4; ++nt) c[1][nt] = __builtin_amdgcn_mfma_f32_16x16x32_bf16(al1, bh[nt], c[1][nt], 0, 0, 0);
#pragma unroll
        for (int nt = 0; nt < 4; ++nt) c[0][nt] = __builtin_amdgcn_mfma_f32_16x16x32_bf16(am0, bm[nt], c[0][nt], 0, 0, 0);
#pragma unroll
        for (int nt = 0; nt < 4; ++nt) c[1][nt] = __builtin_amdgcn_mfma_f32_16x16x32_bf16(am1, bm[nt], c[1][nt], 0, 0, 0);
    }

    // combine the 8 waves' fp32 K-chunk partials in LDS (one-time, proven)
    for (int w = 0; w < 8; ++w) {
        if (wq == w) {
#pragma unroll
            for (int mt = 0; mt < 2; ++mt)
#pragma unroll
                for (int nt = 0; nt < 4; ++nt)
#pragma unroll
                    for (int i = 0; i < 4; ++i) {
                        const int row = mt * 16 + lk * 4 + i;  // token in block
                        const int col = nt * 16 + lrow;        // expert
                        if (w == 0) L[row][col]  = c[mt][nt][i];
                        else        L[row][col] += c[mt][nt][i];
                    }
        }
        __syncthreads();
    }

    float* dispatch = out;
    float* probs    = out + (size_t)TTOT * NEXP;
    float* tkp      = out + (size_t)2 * TTOT * NEXP;
    float* tki      = tkp + (size_t)TTOT * 2;

    // each wave: softmax + top-2 for 4 tokens, lane = expert (proven code)
#pragma unroll
    for (int tt = 0; tt < 4; ++tt) {
        const int te = wq * 4 + tt;
        const int gt = tokBase + te;
        const float Lg = L[te][lane];

        float m = Lg;
#pragma unroll
        for (int off = 32; off; off >>= 1) m = fmaxf(m, __shfl_xor(m, off, 64));
        const float p = expf(Lg - m);
        float sden = p;
#pragma unroll
        for (int off = 32; off; off >>= 1) sden += __shfl_xor(sden, off, 64);
        const float prob = p / sden;

        // top-1 (ties -> lowest index, matching lax.top_k / np)
        float v1 = prob; int i1 = lane;
#pragma unroll
        for (int off = 32; off; off >>= 1) {
            const float ov = __shfl_xor(v1, off, 64);
            const int   oi = __shfl_xor(i1, off, 64);
            if (ov > v1 || (ov == v1 && oi < i1)) { v1 = ov; i1 = oi; }
        }
        // top-2
        float v2 = (lane == i1) ? -1.0f : prob; int i2 = lane;
#pragma unroll
        for (int off = 32; off; off >>= 1) {
            const float ov = __shfl_xor(v2, off, 64);
            const int   oi = __shfl_xor(i2, off, 64);
            if (ov > v2 || (ov == v2 && oi < i2)) { v2 = ov; i2 = oi; }
        }

        probs[(size_t)gt * NEXP + lane]    = prob;
        dispatch[(size_t)gt * NEXP + lane] = (lane == i1 || lane == i2) ? 1.0f : 0.0f;
        if (lane == 0) {
            tkp[(size_t)gt * 2 + 0] = v1;
            tkp[(size_t)gt * 2 + 1] = v2;
            tki[(size_t)gt * 2 + 0] = (float)i1;
            tki[(size_t)gt * 2 + 1] = (float)i2;
        }
    }
}

extern "C" void kernel_launch(void* const* d_in, const int* in_sizes, int n_in,
                              void* d_out, int out_size, void* d_ws, size_t ws_size,
                              hipStream_t stream) {
    const float* x = (const float*)d_in[0];
    const float* W = (const float*)d_in[1];
    float* out = (float*)d_out;
    unsigned short* W4 = (unsigned short*)d_ws;   // 3 * 131072 * 2B = 768 KB

    w_split<<<512, 256, 0, stream>>>(W, W4);
    moe_gemm<<<TTOT / TPB, 512, 0, stream>>>(x, W4, out);
}

// Round 7
// 217.708 us; speedup vs baseline: 1.0615x; 1.0615x over previous
//
#include <hip/hip_runtime.h>

#define TTOT 16384        // 4 * 4096 tokens
#define DDIM 2048
#define NEXP 64
#define WTERM (NEXP * DDIM)   // 131072 elems per split term

// v6 GEMM geometry: 128 tokens x 64 experts x 512-d K-quarter per block
#define MBLK 128
#define KSPL 4
#define KBLK (DDIM / KSPL)    // 512
#define NKS6 (KBLK / 32)      // 16 k-steps
// fallback (R4) geometry
#define TPB  32
#define KCH  256
#define NKS  8

typedef __attribute__((ext_vector_type(8))) short bf16x8;
typedef __attribute__((ext_vector_type(4))) float f32x4;
typedef __attribute__((ext_vector_type(4))) unsigned int u32x4;

// ---------------------------------------------------------------------------
// Exact fp32 -> 3x bf16 truncation split (proven R3/R4). x == xh + xm + xl.
// ---------------------------------------------------------------------------
__device__ __forceinline__ void split3(const f32x4 va, const f32x4 vb,
                                       bf16x8& h, bf16x8& m, bf16x8& l)
{
    const float f[8] = {va.x, va.y, va.z, va.w, vb.x, vb.y, vb.z, vb.w};
    unsigned int hu[8], mu[8], lu[8];
#pragma unroll
    for (int j = 0; j < 8; ++j) {
        const unsigned int xb = __float_as_uint(f[j]);
        const unsigned int hb = xb & 0xffff0000u;
        const float r1 = f[j] - __uint_as_float(hb);
        const unsigned int mb = __float_as_uint(r1) & 0xffff0000u;
        const float r2 = r1 - __uint_as_float(mb);
        hu[j] = hb; mu[j] = mb; lu[j] = __float_as_uint(r2);
    }
    u32x4 hw, mw, lw;
#pragma unroll
    for (int w = 0; w < 4; ++w) {
        hw[w] = (hu[2 * w] >> 16) | (hu[2 * w + 1] & 0xffff0000u);
        mw[w] = (mu[2 * w] >> 16) | (mu[2 * w + 1] & 0xffff0000u);
        lw[w] = (lu[2 * w] >> 16) | (lu[2 * w + 1] & 0xffff0000u);
    }
    h = __builtin_bit_cast(bf16x8, hw);
    m = __builtin_bit_cast(bf16x8, mw);
    l = __builtin_bit_cast(bf16x8, lw);
}

// ---------------------------------------------------------------------------
// Prep: split W [2048][64] fp32 into W4[3][256 kg][64 e][8 d] bf16.
// ---------------------------------------------------------------------------
__global__ __launch_bounds__(256)
void w_split(const float* __restrict__ W, unsigned short* __restrict__ W4)
{
    const int q = blockIdx.x * 256 + threadIdx.x;   // 0 .. 131071
    const int e = q >> 11;                          // 0..63
    const int d = q & 2047;                         // 0..2047
    const float w = W[(size_t)d * NEXP + e];
    const unsigned int xb = __float_as_uint(w);
    const unsigned int hb = xb & 0xffff0000u;
    const float r1 = w - __uint_as_float(hb);
    const unsigned int mb = __float_as_uint(r1) & 0xffff0000u;
    const float r2 = r1 - __uint_as_float(mb);
    const unsigned int lb = __float_as_uint(r2);
    const size_t o = ((size_t)(d >> 3) * 64 + e) * 8 + (d & 7);
    W4[o]             = (unsigned short)(hb >> 16);
    W4[o + WTERM]     = (unsigned short)(mb >> 16);
    W4[o + 2 * WTERM] = (unsigned short)(lb >> 16);
}

// ---------------------------------------------------------------------------
// v6 GEMM (m97-style): 512 blocks x 256 thr (4 waves). Block (mblk, kblk)
// computes partial logits for tokens [mblk*128, +128) over d-range
// [kblk*512, +512). Per 32-d k-step, A (16 KB, granule-XOR-swizzled via
// pre-swizzled global source) and B (12 KB, 1040B-padded rows, SHARED by
// all 4 waves) are staged ONE STEP AHEAD via global_load_lds into double
// buffers; one __syncthreads (compiler-emitted vmcnt drain) per step.
// Nothing is consumed in the iteration it is loaded. Wave wq: 32 tokens x
// 64 experts, 48 MFMA/step (verbatim R3 pass order). Partials -> pl.
// ---------------------------------------------------------------------------
__global__ __launch_bounds__(256, 2)
void moe_gemm6(const float* __restrict__ x, const unsigned short* __restrict__ W4,
               float* __restrict__ pl)
{
    __shared__ float as[2][MBLK][32];                    // 32 KB
    __shared__ __align__(16) unsigned char bs[2][3][4][1040];  // 24.96 KB
    const int tid  = threadIdx.x;
    const int lane = tid & 63;
    const int wq   = __builtin_amdgcn_readfirstlane(tid >> 6);  // 0..3
    const int lrow = lane & 15;          // A row (token) / B col (expert)
    const int lk   = lane >> 4;          // k-group (0..3)
    const int kblk = blockIdx.x & 3;
    const int mblk = blockIdx.x >> 2;
    const int tokBase = mblk * MBLK;
    const int kBase   = kblk * KBLK;

    f32x4 c[2][4];
#pragma unroll
    for (int mt = 0; mt < 2; ++mt)
#pragma unroll
        for (int nt = 0; nt < 4; ++nt)
            c[mt][nt] = (f32x4){0.0f, 0.0f, 0.0f, 0.0f};

    // --- A staging map: granule gi = cc*256+tid; token t = gi>>3, phys col
    // p = gi&7 holds logical granule g = p ^ (t&7) (inverse swizzle applied
    // to the global source; LDS dest stays linear -> rule 21 satisfied).
    const float* aSrc[4];
    int aDstOff[4];
#pragma unroll
    for (int cc = 0; cc < 4; ++cc) {
        const int gi = cc * 256 + tid;
        const int t  = gi >> 3;
        const int g  = (gi & 7) ^ (t & 7);
        aSrc[cc]    = x + (size_t)(tokBase + t) * DDIM + kBase + g * 4;
        aDstOff[cc] = gi * 16;
    }
    // --- B staging map: call cc, wave wq -> (term, kg-row); 64 lanes = row.
    const unsigned short* bSrc[3];
    int bDstOff[3];
#pragma unroll
    for (int cc = 0; cc < 3; ++cc) {
        const int q2   = cc * 4 + wq;
        const int term = q2 >> 2;            // 0..2
        const int row  = q2 & 3;             // 0..3
        bSrc[cc]    = W4 + (size_t)term * WTERM + ((kBase >> 3) + row) * 512 + lane * 8;
        bDstOff[cc] = term * 4160 + row * 1040 + lane * 16;
    }

#define STAGE6(ksn, dbuf)                                                      \
    {                                                                          \
        unsigned char* aB = (unsigned char*)&as[dbuf][0][0];                   \
        unsigned char* bB = &bs[dbuf][0][0][0];                                \
        _Pragma("unroll")                                                      \
        for (int cc = 0; cc < 4; ++cc)                                         \
            __builtin_amdgcn_global_load_lds(                                  \
                (const __attribute__((address_space(1))) unsigned int*)        \
                    (aSrc[cc] + (ksn) * 32),                                   \
                (__attribute__((address_space(3))) unsigned int*)              \
                    (aB + aDstOff[cc]), 16, 0, 0);                             \
        _Pragma("unroll")                                                      \
        for (int cc = 0; cc < 3; ++cc)                                         \
            __builtin_amdgcn_global_load_lds(                                  \
                (const __attribute__((address_space(1))) unsigned int*)        \
                    (bSrc[cc] + (ksn) * 2048),                                 \
                (__attribute__((address_space(3))) unsigned int*)              \
                    (bB + bDstOff[cc]), 16, 0, 0);                             \
    }

    // A read addressing (logical granule lk*2 lives at phys (lk*2)^(t&7))
    const int t0 = wq * 32 + lrow;
    const int t1 = t0 + 16;
    const int q0 = (lk * 2) ^ (t0 & 7);
    const int q1 = (lk * 2) ^ (t1 & 7);
    const int aOff0 = t0 * 32 + q0 * 4;
    const int aOff1 = t1 * 32 + q1 * 4;

    // prologue
    STAGE6(0, 0)
    __syncthreads();

#pragma unroll 2
    for (int ks = 0; ks < NKS6; ++ks) {
        const int buf = ks & 1;
        if (ks + 1 < NKS6) STAGE6(ks + 1, buf ^ 1)

        // B fragments from shared LDS
        const unsigned char* bb = &bs[buf][0][0][0];
        bf16x8 bh[4], bm[4], bl[4];
#pragma unroll
        for (int nt = 0; nt < 4; ++nt) {
            const int eo = (nt * 16 + lrow) * 16 + lk * 1040;
            bh[nt] = *(const bf16x8*)(bb + eo);
            bm[nt] = *(const bf16x8*)(bb + 4160 + eo);
            bl[nt] = *(const bf16x8*)(bb + 8320 + eo);
        }

        // A fragments (swizzled read) + exact split
        const float* sub = &as[buf][0][0];
        const f32x4 c0a = *(const f32x4*)(sub + aOff0);
        const f32x4 c0b = *(const f32x4*)(sub + (aOff0 ^ 4));
        const f32x4 c1a = *(const f32x4*)(sub + aOff1);
        const f32x4 c1b = *(const f32x4*)(sub + (aOff1 ^ 4));
        bf16x8 ah0, am0, al0, ah1, am1, al1;
        split3(c0a, c0b, ah0, am0, al0);
        split3(c1a, c1b, ah1, am1, al1);

        // 6 passes x 2 M x 4 N = 48 MFMA (verbatim R3 order)
#pragma unroll
        for (int nt = 0; nt < 4; ++nt) c[0][nt] = __builtin_amdgcn_mfma_f32_16x16x32_bf16(ah0, bh[nt], c[0][nt], 0, 0, 0);
#pragma unroll
        for (int nt = 0; nt < 4; ++nt) c[1][nt] = __builtin_amdgcn_mfma_f32_16x16x32_bf16(ah1, bh[nt], c[1][nt], 0, 0, 0);
#pragma unroll
        for (int nt = 0; nt < 4; ++nt) c[0][nt] = __builtin_amdgcn_mfma_f32_16x16x32_bf16(ah0, bm[nt], c[0][nt], 0, 0, 0);
#pragma unroll
        for (int nt = 0; nt < 4; ++nt) c[1][nt] = __builtin_amdgcn_mfma_f32_16x16x32_bf16(ah1, bm[nt], c[1][nt], 0, 0, 0);
#pragma unroll
        for (int nt = 0; nt < 4; ++nt) c[0][nt] = __builtin_amdgcn_mfma_f32_16x16x32_bf16(am0, bh[nt], c[0][nt], 0, 0, 0);
#pragma unroll
        for (int nt = 0; nt < 4; ++nt) c[1][nt] = __builtin_amdgcn_mfma_f32_16x16x32_bf16(am1, bh[nt], c[1][nt], 0, 0, 0);
#pragma unroll
        for (int nt = 0; nt < 4; ++nt) c[0][nt] = __builtin_amdgcn_mfma_f32_16x16x32_bf16(ah0, bl[nt], c[0][nt], 0, 0, 0);
#pragma unroll
        for (int nt = 0; nt < 4; ++nt) c[1][nt] = __builtin_amdgcn_mfma_f32_16x16x32_bf16(ah1, bl[nt], c[1][nt], 0, 0, 0);
#pragma unroll
        for (int nt = 0; nt < 4; ++nt) c[0][nt] = __builtin_amdgcn_mfma_f32_16x16x32_bf16(al0, bh[nt], c[0][nt], 0, 0, 0);
#pragma unroll
        for (int nt = 0; nt < 4; ++nt) c[1][nt] = __builtin_amdgcn_mfma_f32_16x16x32_bf16(al1, bh[nt], c[1][nt], 0, 0, 0);
#pragma unroll
        for (int nt = 0; nt < 4; ++nt) c[0][nt] = __builtin_amdgcn_mfma_f32_16x16x32_bf16(am0, bm[nt], c[0][nt], 0, 0, 0);
#pragma unroll
        for (int nt = 0; nt < 4; ++nt) c[1][nt] = __builtin_amdgcn_mfma_f32_16x16x32_bf16(am1, bm[nt], c[1][nt], 0, 0, 0);

        __syncthreads();   // compiler emits vmcnt(0) lgkmcnt(0) drain here
    }
#undef STAGE6

    // write fp32 partials (disjoint per wave; no combine needed)
    float* plp = pl + (size_t)kblk * TTOT * NEXP;
#pragma unroll
    for (int mt = 0; mt < 2; ++mt)
#pragma unroll
        for (int nt = 0; nt < 4; ++nt)
#pragma unroll
            for (int i = 0; i < 4; ++i) {
                const int row = tokBase + wq * 32 + mt * 16 + lk * 4 + i;
                const int col = nt * 16 + lrow;
                plp[(size_t)row * NEXP + col] = c[mt][nt][i];
            }
}

// ---------------------------------------------------------------------------
// Finish: sum the 4 K-split partials (fixed order) + proven softmax/top-2.
// 512 blocks x 256 thr; wave handles 8 tokens, lane = expert.
// ---------------------------------------------------------------------------
__global__ __launch_bounds__(256)
void moe_finish(const float* __restrict__ pl, float* __restrict__ out)
{
    const int tid  = threadIdx.x;
    const int lane = tid & 63;
    const int wq   = __builtin_amdgcn_readfirstlane(tid >> 6);  // 0..3
    const int tokBase = blockIdx.x * 32;

    float* dispatch = out;
    float* probs    = out + (size_t)TTOT * NEXP;
    float* tkp      = out + (size_t)2 * TTOT * NEXP;
    float* tki      = tkp + (size_t)TTOT * 2;

#pragma unroll
    for (int tt = 0; tt < 8; ++tt) {
        const int gt = tokBase + wq * 8 + tt;
        const size_t o = (size_t)gt * NEXP + lane;
        float Lg = pl[o];
        Lg += pl[o + (size_t)TTOT * NEXP];
        Lg += pl[o + (size_t)2 * TTOT * NEXP];
        Lg += pl[o + (size_t)3 * TTOT * NEXP];

        float m = Lg;
#pragma unroll
        for (int off = 32; off; off >>= 1) m = fmaxf(m, __shfl_xor(m, off, 64));
        const float p = expf(Lg - m);
        float sden = p;
#pragma unroll
        for (int off = 32; off; off >>= 1) sden += __shfl_xor(sden, off, 64);
        const float prob = p / sden;

        float v1 = prob; int i1 = lane;
#pragma unroll
        for (int off = 32; off; off >>= 1) {
            const float ov = __shfl_xor(v1, off, 64);
            const int   oi = __shfl_xor(i1, off, 64);
            if (ov > v1 || (ov == v1 && oi < i1)) { v1 = ov; i1 = oi; }
        }
        float v2 = (lane == i1) ? -1.0f : prob; int i2 = lane;
#pragma unroll
        for (int off = 32; off; off >>= 1) {
            const float ov = __shfl_xor(v2, off, 64);
            const int   oi = __shfl_xor(i2, off, 64);
            if (ov > v2 || (ov == v2 && oi < i2)) { v2 = ov; i2 = oi; }
        }

        probs[(size_t)gt * NEXP + lane]    = prob;
        dispatch[(size_t)gt * NEXP + lane] = (lane == i1 || lane == i2) ? 1.0f : 0.0f;
        if (lane == 0) {
            tkp[(size_t)gt * 2 + 0] = v1;
            tkp[(size_t)gt * 2 + 1] = v2;
            tki[(size_t)gt * 2 + 0] = (float)i1;
            tki[(size_t)gt * 2 + 1] = (float)i2;
        }
    }
}

// ---------------------------------------------------------------------------
// Fallback (R4-proven, ~75us GEMM): used only if ws_size is too small.
// ---------------------------------------------------------------------------
__global__ __launch_bounds__(512, 4)
void moe_gemm_fb(const float* __restrict__ x, const unsigned short* __restrict__ W4,
                 float* __restrict__ out)
{
    __shared__ float xs[2][8][32][32];
    __shared__ float L[TPB][NEXP + 1];
    const int tid  = threadIdx.x;
    const int lane = tid & 63;
    const int wq   = __builtin_amdgcn_readfirstlane(tid >> 6);
    const int lrow = lane & 15;
    const int lk   = lane >> 4;
    const int tokBase = blockIdx.x * TPB;
    const int kBase   = wq * KCH;

    f32x4 c[2][4];
#pragma unroll
    for (int mt = 0; mt < 2; ++mt)
#pragma unroll
        for (int nt = 0; nt < 4; ++nt)
            c[mt][nt] = (f32x4){0.0f, 0.0f, 0.0f, 0.0f};

    const int srow = lane >> 3;
    const int scol = (lane & 7) ^ srow;
    const float* sBase = x + (size_t)(tokBase + srow) * DDIM + kBase + scol * 4;

#define STAGEF(ksn, dstbuf)                                                    \
    {                                                                          \
        const float* g_ = sBase + (ksn) * 32;                                  \
        float* l_ = &xs[dstbuf][wq][0][0];                                     \
        _Pragma("unroll")                                                      \
        for (int cc = 0; cc < 4; ++cc)                                         \
            __builtin_amdgcn_global_load_lds(                                  \
                (const __attribute__((address_space(1))) unsigned int*)        \
                    (g_ + cc * 8 * DDIM),                                      \
                (__attribute__((address_space(3))) unsigned int*)              \
                    (l_ + cc * 256), 16, 0, 0);                                \
    }

    const int ph    = (lk * 2) ^ (lrow & 7);
    const int aoff0 = lrow * 32 + ph * 4;
    const int aoff1 = (16 + lrow) * 32 + ph * 4;

    const unsigned short* bph = W4 + (size_t)(((kBase >> 3) + lk) * 512 + lrow * 8);
    const unsigned short* bpm = bph + WTERM;
    const unsigned short* bpl = bpm + WTERM;

    STAGEF(0, 0)

#pragma unroll 2
    for (int ks = 0; ks < NKS; ++ks) {
        asm volatile("s_waitcnt vmcnt(0)" ::: "memory");
        const int buf = ks & 1;
        if (ks + 1 < NKS) STAGEF(ks + 1, buf ^ 1)

        bf16x8 bh[4], bm[4], bl[4];
#pragma unroll
        for (int nt = 0; nt < 4; ++nt) {
            bh[nt] = *(const bf16x8*)(bph + ks * 2048 + nt * 128);
            bm[nt] = *(const bf16x8*)(bpm + ks * 2048 + nt * 128);
            bl[nt] = *(const bf16x8*)(bpl + ks * 2048 + nt * 128);
        }

        const float* sub = &xs[buf][wq][0][0];
        const f32x4 c0a = *(const f32x4*)(sub + aoff0);
        const f32x4 c0b = *(const f32x4*)(sub + (aoff0 ^ 4));
        const f32x4 c1a = *(const f32x4*)(sub + aoff1);
        const f32x4 c1b = *(const f32x4*)(sub + (aoff1 ^ 4));
        bf16x8 ah0, am0, al0, ah1, am1, al1;
        split3(c0a, c0b, ah0, am0, al0);
        split3(c1a, c1b, ah1, am1, al1);

#pragma unroll
        for (int nt = 0; nt < 4; ++nt) c[0][nt] = __builtin_amdgcn_mfma_f32_16x16x32_bf16(ah0, bh[nt], c[0][nt], 0, 0, 0);
#pragma unroll
        for (int nt = 0; nt < 4; ++nt) c[1][nt] = __builtin_amdgcn_mfma_f32_16x16x32_bf16(ah1, bh[nt], c[1][nt], 0, 0, 0);
#pragma unroll
        for (int nt = 0; nt < 4; ++nt) c[0][nt] = __builtin_amdgcn_mfma_f32_16x16x32_bf16(ah0, bm[nt], c[0][nt], 0, 0, 0);
#pragma unroll
        for (int nt = 0; nt < 4; ++nt) c[1][nt] = __builtin_amdgcn_mfma_f32_16x16x32_bf16(ah1, bm[nt], c[1][nt], 0, 0, 0);
#pragma unroll
        for (int nt = 0; nt < 4; ++nt) c[0][nt] = __builtin_amdgcn_mfma_f32_16x16x32_bf16(am0, bh[nt], c[0][nt], 0, 0, 0);
#pragma unroll
        for (int nt = 0; nt < 4; ++nt) c[1][nt] = __builtin_amdgcn_mfma_f32_16x16x32_bf16(am1, bh[nt], c[1][nt], 0, 0, 0);
#pragma unroll
        for (int nt = 0; nt < 4; ++nt) c[0][nt] = __builtin_amdgcn_mfma_f32_16x16x32_bf16(ah0, bl[nt], c[0][nt], 0, 0, 0);
#pragma unroll
        for (int nt = 0; nt < 4; ++nt) c[1][nt] = __builtin_amdgcn_mfma_f32_16x16x32_bf16(ah1, bl[nt], c[1][nt], 0, 0, 0);
#pragma unroll
        for (int nt = 0; nt < 4; ++nt) c[0][nt] = __builtin_amdgcn_mfma_f32_16x16x32_bf16(al0, bh[nt], c[0][nt], 0, 0, 0);
#pragma unroll
        for (int nt = 0; nt < 4; ++nt) c[1][nt] = __builtin_amdgcn_mfma_f32_16x16x32_bf16(al1, bh[nt], c[1][nt], 0, 0, 0);
#pragma unroll
        for (int nt = 0; nt < 4; ++nt) c[0][nt] = __builtin_amdgcn_mfma_f32_16x16x32_bf16(am0, bm[nt], c[0][nt], 0, 0, 0);
#pragma unroll
        for (int nt = 0; nt < 4; ++nt) c[1][nt] = __builtin_amdgcn_mfma_f32_16x16x32_bf16(am1, bm[nt], c[1][nt], 0, 0, 0);
    }
#undef STAGEF

    for (int w = 0; w < 8; ++w) {
        if (wq == w) {
#pragma unroll
            for (int mt = 0; mt < 2; ++mt)
#pragma unroll
                for (int nt = 0; nt < 4; ++nt)
#pragma unroll
                    for (int i = 0; i < 4; ++i) {
                        const int row = mt * 16 + lk * 4 + i;
                        const int col = nt * 16 + lrow;
                        if (w == 0) L[row][col]  = c[mt][nt][i];
                        else        L[row][col] += c[mt][nt][i];
                    }
        }
        __syncthreads();
    }

    float* dispatch = out;
    float* probs    = out + (size_t)TTOT * NEXP;
    float* tkp      = out + (size_t)2 * TTOT * NEXP;
    float* tki      = tkp + (size_t)TTOT * 2;

#pragma unroll
    for (int tt = 0; tt < 4; ++tt) {
        const int te = wq * 4 + tt;
        const int gt = tokBase + te;
        const float Lg = L[te][lane];

        float m = Lg;
#pragma unroll
        for (int off = 32; off; off >>= 1) m = fmaxf(m, __shfl_xor(m, off, 64));
        const float p = expf(Lg - m);
        float sden = p;
#pragma unroll
        for (int off = 32; off; off >>= 1) sden += __shfl_xor(sden, off, 64);
        const float prob = p / sden;

        float v1 = prob; int i1 = lane;
#pragma unroll
        for (int off = 32; off; off >>= 1) {
            const float ov = __shfl_xor(v1, off, 64);
            const int   oi = __shfl_xor(i1, off, 64);
            if (ov > v1 || (ov == v1 && oi < i1)) { v1 = ov; i1 = oi; }
        }
        float v2 = (lane == i1) ? -1.0f : prob; int i2 = lane;
#pragma unroll
        for (int off = 32; off; off >>= 1) {
            const float ov = __shfl_xor(v2, off, 64);
            const int   oi = __shfl_xor(i2, off, 64);
            if (ov > v2 || (ov == v2 && oi < i2)) { v2 = ov; i2 = oi; }
        }

        probs[(size_t)gt * NEXP + lane]    = prob;
        dispatch[(size_t)gt * NEXP + lane] = (lane == i1 || lane == i2) ? 1.0f : 0.0f;
        if (lane == 0) {
            tkp[(size_t)gt * 2 + 0] = v1;
            tkp[(size_t)gt * 2 + 1] = v2;
            tki[(size_t)gt * 2 + 0] = (float)i1;
            tki[(size_t)gt * 2 + 1] = (float)i2;
        }
    }
}

extern "C" void kernel_launch(void* const* d_in, const int* in_sizes, int n_in,
                              void* d_out, int out_size, void* d_ws, size_t ws_size,
                              hipStream_t stream) {
    const float* x = (const float*)d_in[0];
    const float* W = (const float*)d_in[1];
    float* out = (float*)d_out;
    unsigned short* W4 = (unsigned short*)d_ws;     // 768 KB at offset 0

    w_split<<<512, 256, 0, stream>>>(W, W4);

    const size_t plOff  = 1u << 20;                              // 1 MB
    const size_t plSize = (size_t)KSPL * TTOT * NEXP * 4;        // 16.8 MB
    if (ws_size >= plOff + plSize) {
        float* pl = (float*)((char*)d_ws + plOff);
        moe_gemm6<<<(TTOT / MBLK) * KSPL, 256, 0, stream>>>(x, W4, pl);
        moe_finish<<<TTOT / 32, 256, 0, stream>>>(pl, out);
    } else {
        moe_gemm_fb<<<TTOT / TPB, 512, 0, stream>>>(x, W4, out);
    }
}